// Round 4
// baseline (1149.309 us; speedup 1.0000x reference)
//
#include <hip/hip_runtime.h>
#include <math.h>

namespace {
constexpr int B_  = 8;
constexpr int U_  = 16384;
constexpr int S_  = 4096;
constexpr int E_  = 128;
constexpr int NTOK  = B_ * U_;   // 131072
constexpr int NCELL = B_ * S_;   // 32768
}

typedef __attribute__((ext_vector_type(8))) short bf16x8;
typedef __attribute__((ext_vector_type(4))) float f32x4;

__device__ inline unsigned short bf16rne(float x) {
  unsigned u = __float_as_uint(x);
  u = u + 0x7fffu + ((u >> 16) & 1u);
  return (unsigned short)(u >> 16);
}

__device__ inline bf16x8 pack8(float4 a, float4 b) {
  bf16x8 r;
  r[0] = (short)bf16rne(a.x); r[1] = (short)bf16rne(a.y);
  r[2] = (short)bf16rne(a.z); r[3] = (short)bf16rne(a.w);
  r[4] = (short)bf16rne(b.x); r[5] = (short)bf16rne(b.y);
  r[6] = (short)bf16rne(b.z); r[7] = (short)bf16rne(b.w);
  return r;
}

// ------------------------------------------------------------------
// P0: swizzle weights fp32 -> bf16 B-fragment layout.
// ------------------------------------------------------------------
__global__ __launch_bounds__(256) void prep_weights(
    const float* __restrict__ Wq, const float* __restrict__ Wk,
    const float* __restrict__ Wv, const float* __restrict__ Wo,
    unsigned short* __restrict__ dst) {
  const int i = blockIdx.x * 256 + threadIdx.x;
  const int w = i >> 14, e = i & 16383;
  const int k = e >> 7, n = e & 127;
  const float* src = (w == 0) ? Wq : (w == 1) ? Wk : (w == 2) ? Wv : Wo;
  dst[w * 16384 + (((k >> 3) * 128 + n) << 3) + (k & 7)] = bf16rne(src[e]);
}

// ------------------------------------------------------------------
// Sort pipeline: zero counts -> bucketize+count -> scan -> scatter ids
// ------------------------------------------------------------------
__global__ __launch_bounds__(256) void zero_cnt(int* __restrict__ cnt) {
  cnt[blockIdx.x * 256 + threadIdx.x] = 0;
}

__global__ __launch_bounds__(256) void bucketize_count(
    const float* __restrict__ xc_off, int* __restrict__ seg_arr,
    int* __restrict__ cnt) {
  const int tok = blockIdx.x * 256 + threadIdx.x;
  const int b = tok >> 14;
  // EXACT replication of reference fp32 bucketize math
  const float sp = 1.0f / 63.0f;
  const float half = sp * 0.5f;
  const float x0 = xc_off[(size_t)tok * 2 + 0];
  const float x1 = xc_off[(size_t)tok * 2 + 1];
  float n0 = floorf((x0 - 0.0f + half) / sp);
  float n1 = floorf((x1 - 0.0f + half) / sp);
  n0 = fminf(fmaxf(n0, 0.0f), 63.0f);
  n1 = fminf(fmaxf(n1, 0.0f), 63.0f);
  const int seg = b * S_ + (int)(n0 * 64.0f + n1);
  seg_arr[tok] = seg;
  atomicAdd(&cnt[seg], 1);
}

__global__ __launch_bounds__(1024) void scan_kernel(
    const int* __restrict__ cnt, int* __restrict__ offs, int* __restrict__ cursor) {
  __shared__ int sh[1024];
  const int tid = threadIdx.x;
  const int base = tid * 32;
  int local[32];
  int tot = 0;
#pragma unroll
  for (int i = 0; i < 32; ++i) { local[i] = cnt[base + i]; tot += local[i]; }
  sh[tid] = tot;
  __syncthreads();
  for (int ofs = 1; ofs < 1024; ofs <<= 1) {
    int v = (tid >= ofs) ? sh[tid - ofs] : 0;
    __syncthreads();
    sh[tid] += v;
    __syncthreads();
  }
  int run = sh[tid] - tot;   // exclusive prefix for this thread's range
#pragma unroll
  for (int i = 0; i < 32; ++i) {
    offs[base + i] = run;
    cursor[base + i] = run;
    run += local[i];
  }
  if (tid == 1023) offs[NCELL] = run;   // == NTOK
}

__global__ __launch_bounds__(256) void scatter_ids(
    const int* __restrict__ seg_arr, int* __restrict__ cursor,
    int* __restrict__ sorted) {
  const int tok = blockIdx.x * 256 + threadIdx.x;
  const int seg = seg_arr[tok];
  const int r = atomicAdd(&cursor[seg], 1);
  sorted[r] = tok;
}

// ------------------------------------------------------------------
// K0: Qp = 0.25 * latents @ Wq, stored transposed-in-row: Qp[s][d*8+h]
// ------------------------------------------------------------------
__global__ __launch_bounds__(512, 4) void qproj_mfma(
    const float* __restrict__ latents, const unsigned short* __restrict__ Wq_sw,
    float* __restrict__ Qp) {
  __shared__ __align__(16) unsigned short wq[16384];
  const int tid = threadIdx.x;
  {
    const uint4* s = (const uint4*)Wq_sw;
    uint4* d = (uint4*)wq;
#pragma unroll
    for (int i = 0; i < 4; ++i) d[i * 512 + tid] = s[i * 512 + tid];
  }
  __syncthreads();

  const int wave = tid >> 6, lane = tid & 63;
  const int c = lane & 15, g = lane >> 4;
  const int t0w = blockIdx.x * 128 + wave * 16;

  f32x4 acc[8];
#pragma unroll
  for (int i = 0; i < 8; ++i) acc[i] = {0.f, 0.f, 0.f, 0.f};

  const float* arow = latents + (size_t)(t0w + c) * E_ + g * 8;
  const bf16x8* bq = (const bf16x8*)wq;
#pragma unroll
  for (int ks = 0; ks < 4; ++ks) {
    float4 a0 = *(const float4*)(arow + ks * 32);
    float4 a1 = *(const float4*)(arow + ks * 32 + 4);
    bf16x8 af = pack8(a0, a1);
    const int bo = (ks * 4 + g) * 128 + c;
#pragma unroll
    for (int nt = 0; nt < 8; ++nt)
      acc[nt] = __builtin_amdgcn_mfma_f32_16x16x32_bf16(af, bq[bo + nt * 16], acc[nt], 0, 0, 0);
  }
#pragma unroll
  for (int nt = 0; nt < 8; ++nt)
#pragma unroll
    for (int r = 0; r < 4; ++r)
      Qp[(size_t)(t0w + g * 4 + r) * E_ + c * 8 + nt] = acc[nt][r] * 0.25f;
}

// ------------------------------------------------------------------
// KF: fused per-cell kernel. One wave owns one cell:
//   gather its sorted off-grid tokens (+ on-grid token folded in),
//   K/V MFMA, w=exp(q.k) (pads weight-0), reduce num/denom in regs,
//   store normalized num directly into out. ZERO scatter atomics.
// ------------------------------------------------------------------
__global__ __launch_bounds__(512, 4) void fused_cells(
    const float* __restrict__ zc_off, const float* __restrict__ zc_on,
    const float* __restrict__ fake, const int* __restrict__ ignore_flag,
    const unsigned short* __restrict__ Wk_sw, const unsigned short* __restrict__ Wv_sw,
    const float* __restrict__ Qp, const int* __restrict__ offs,
    const int* __restrict__ sorted, float* __restrict__ out) {
  __shared__ __align__(16) unsigned short wk[16384];
  __shared__ __align__(16) unsigned short wv[16384];
  const int tid = threadIdx.x;
  {
    const uint4* sk = (const uint4*)Wk_sw;
    const uint4* sv = (const uint4*)Wv_sw;
    uint4* dk = (uint4*)wk; uint4* dv = (uint4*)wv;
#pragma unroll
    for (int i = 0; i < 4; ++i) {
      dk[i * 512 + tid] = sk[i * 512 + tid];
      dv[i * 512 + tid] = sv[i * 512 + tid];
    }
  }
  const int ign = *ignore_flag;
  __syncthreads();

  const int wave = tid >> 6, lane = tid & 63;
  const int c = lane & 15, g = lane >> 4;
  const int cell = blockIdx.x * 8 + wave;     // token = b*S + s
  const int s = cell & (S_ - 1);
  const int base = offs[cell];
  const int n_off = offs[cell + 1] - base;

  // this cell's q (one cell per wave): Qp[s][c*8 + h]
  const f32x4 qa = *(const f32x4*)(Qp + (size_t)s * E_ + c * 8);
  const f32x4 qb = *(const f32x4*)(Qp + (size_t)s * E_ + c * 8 + 4);

  float num_acc[8], den_acc[8];
#pragma unroll
  for (int i = 0; i < 8; ++i) { num_acc[i] = 0.f; den_acc[i] = 0.f; }

  const bf16x8* bk = (const bf16x8*)wk;
  const bf16x8* bv = (const bf16x8*)wv;
  const int chunks = (n_off + 16) >> 4;       // ceil((n_off+1)/16)

  for (int ch = 0; ch < chunks; ++ch) {
    const int idx = ch * 16 + c;              // this lane's token slot
    const float* arow;
    if (idx < n_off)       arow = zc_off + (size_t)sorted[base + idx] * E_;
    else if (idx == n_off) arow = ign ? fake : (zc_on + (size_t)cell * E_);
    else                   arow = zc_on;      // pad: any valid row, weight forced 0
    arow += g * 8;

    f32x4 accK[8], accV[8];
#pragma unroll
    for (int i = 0; i < 8; ++i) { accK[i] = {0.f,0.f,0.f,0.f}; accV[i] = {0.f,0.f,0.f,0.f}; }

#pragma unroll
    for (int ks = 0; ks < 4; ++ks) {
      float4 a0 = *(const float4*)(arow + ks * 32);
      float4 a1 = *(const float4*)(arow + ks * 32 + 4);
      bf16x8 af = pack8(a0, a1);
      const int bo = (ks * 4 + g) * 128 + c;
#pragma unroll
      for (int nt = 0; nt < 8; ++nt) {
        accK[nt] = __builtin_amdgcn_mfma_f32_16x16x32_bf16(af, bk[bo + nt * 16], accK[nt], 0, 0, 0);
        accV[nt] = __builtin_amdgcn_mfma_f32_16x16x32_bf16(af, bv[bo + nt * 16], accV[nt], 0, 0, 0);
      }
    }

    // weights + accumulate (h == nt head pairing; e = nt*16 + c)
#pragma unroll
    for (int h = 0; h < 8; ++h) {
      float w[4];
#pragma unroll
      for (int r = 0; r < 4; ++r) {
        const float qv = (h < 4) ? qa[h] : qb[h - 4];
        float p = accK[h][r] * qv;
        p += __shfl_xor(p, 1, 64); p += __shfl_xor(p, 2, 64);
        p += __shfl_xor(p, 4, 64); p += __shfl_xor(p, 8, 64);
        const int tr = ch * 16 + g * 4 + r;
        w[r] = (tr <= n_off) ? __expf(p) : 0.f;
      }
      float sv = 0.f, sd = 0.f;
#pragma unroll
      for (int r = 0; r < 4; ++r) { sv = fmaf(w[r], accV[h][r], sv); sd += w[r]; }
      num_acc[h] += sv;
      den_acc[h] += sd;
    }
  }

  // reduce over g (lane bits 4..5), then normalize and store
#pragma unroll
  for (int i = 0; i < 8; ++i) {
    num_acc[i] += __shfl_xor(num_acc[i], 16, 64);
    num_acc[i] += __shfl_xor(num_acc[i], 32, 64);
    den_acc[i] += __shfl_xor(den_acc[i], 16, 64);
    den_acc[i] += __shfl_xor(den_acc[i], 32, 64);
  }
#pragma unroll
  for (int b = 0; b < 2; ++b) {
    const int nt = 2 * g + b;
    out[(size_t)cell * E_ + nt * 16 + c] = num_acc[nt] / den_acc[nt];
  }
}

// ------------------------------------------------------------------
// K3: finalize in-place: out = out @ Wo   (out already normalized)
// ------------------------------------------------------------------
__global__ __launch_bounds__(512, 4) void finalize_mfma(
    const unsigned short* __restrict__ Wo_sw, float* __restrict__ out) {
  __shared__ __align__(16) unsigned short wo[16384];
  const int tid = threadIdx.x;
  {
    const uint4* s = (const uint4*)Wo_sw;
    uint4* d = (uint4*)wo;
#pragma unroll
    for (int i = 0; i < 4; ++i) d[i * 512 + tid] = s[i * 512 + tid];
  }
  __syncthreads();

  const int wave = tid >> 6, lane = tid & 63;
  const int c = lane & 15, g = lane >> 4;
  const int t0w = blockIdx.x * 128 + wave * 16;

  f32x4 acc[8];
#pragma unroll
  for (int i = 0; i < 8; ++i) acc[i] = {0.f, 0.f, 0.f, 0.f};

  const float* nrow = out + (size_t)(t0w + c) * E_ + g * 8;
  const bf16x8* bo_ = (const bf16x8*)wo;
#pragma unroll
  for (int ks = 0; ks < 4; ++ks) {
    float4 a0 = *(const float4*)(nrow + ks * 32);
    float4 a1 = *(const float4*)(nrow + ks * 32 + 4);
    bf16x8 af = pack8(a0, a1);
    const int bofs = (ks * 4 + g) * 128 + c;
#pragma unroll
    for (int nt = 0; nt < 8; ++nt)
      acc[nt] = __builtin_amdgcn_mfma_f32_16x16x32_bf16(af, bo_[bofs + nt * 16], acc[nt], 0, 0, 0);
  }
  __syncthreads();   // all reads of this block's rows done before overwrite
#pragma unroll
  for (int nt = 0; nt < 8; ++nt)
#pragma unroll
    for (int r = 0; r < 4; ++r)
      out[(size_t)(t0w + g * 4 + r) * E_ + nt * 16 + c] = acc[nt][r];
}

// ------------------------------------------------------------------
extern "C" void kernel_launch(void* const* d_in, const int* in_sizes, int n_in,
                              void* d_out, int out_size, void* d_ws, size_t ws_size,
                              hipStream_t stream) {
  const float* xc_off  = (const float*)d_in[0];
  const float* zc_off  = (const float*)d_in[2];
  const float* zc_on   = (const float*)d_in[3];
  const float* latents = (const float*)d_in[4];
  const float* fake    = (const float*)d_in[5];
  const float* Wq      = (const float*)d_in[6];
  const float* Wk      = (const float*)d_in[7];
  const float* Wv      = (const float*)d_in[8];
  const float* Wo      = (const float*)d_in[9];
  const int*   ignore  = (const int*)d_in[10];

  float* out = (float*)d_out;

  // workspace layout
  float* Qp = (float*)d_ws;                                  // S*E fp32 (2 MB)
  unsigned short* Wsw = (unsigned short*)(Qp + (size_t)S_ * E_);  // 4x16384 bf16
  int* seg_arr = (int*)(Wsw + 65536);                        // NTOK
  int* cnt     = seg_arr + NTOK;                             // NCELL
  int* offs    = cnt + NCELL;                                // NCELL+1
  int* cursor  = offs + NCELL + 2;                           // NCELL
  int* sorted  = cursor + NCELL;                             // NTOK
  unsigned short* Wq_sw = Wsw;
  unsigned short* Wk_sw = Wsw + 16384;
  unsigned short* Wv_sw = Wsw + 32768;
  unsigned short* Wo_sw = Wsw + 49152;

  prep_weights<<<256, 256, 0, stream>>>(Wq, Wk, Wv, Wo, Wsw);
  zero_cnt<<<NCELL / 256, 256, 0, stream>>>(cnt);
  bucketize_count<<<NTOK / 256, 256, 0, stream>>>(xc_off, seg_arr, cnt);
  scan_kernel<<<1, 1024, 0, stream>>>(cnt, offs, cursor);
  scatter_ids<<<NTOK / 256, 256, 0, stream>>>(seg_arr, cursor, sorted);
  qproj_mfma<<<S_ / 128, 512, 0, stream>>>(latents, Wq_sw, Qp);
  fused_cells<<<NCELL / 8, 512, 0, stream>>>(zc_off, zc_on, fake, ignore,
                                             Wk_sw, Wv_sw, Qp, offs, sorted, out);
  finalize_mfma<<<NCELL / 128, 512, 0, stream>>>(Wo_sw, out);
}

// Round 5
// 250.852 us; speedup vs baseline: 4.5816x; 4.5816x over previous
//
#include <hip/hip_runtime.h>
#include <math.h>

namespace {
constexpr int B_  = 8;
constexpr int U_  = 16384;
constexpr int S_  = 4096;
constexpr int E_  = 128;
constexpr int NTOK  = B_ * U_;   // 131072
constexpr int NCELL = B_ * S_;   // 32768
constexpr int FUSED_GRID = 512;  // persistent blocks (2/CU)
}

typedef __attribute__((ext_vector_type(8))) short bf16x8;
typedef __attribute__((ext_vector_type(4))) float f32x4;

__device__ inline unsigned short bf16rne(float x) {
  unsigned u = __float_as_uint(x);
  u = u + 0x7fffu + ((u >> 16) & 1u);
  return (unsigned short)(u >> 16);
}

__device__ inline bf16x8 pack8(float4 a, float4 b) {
  bf16x8 r;
  r[0] = (short)bf16rne(a.x); r[1] = (short)bf16rne(a.y);
  r[2] = (short)bf16rne(a.z); r[3] = (short)bf16rne(a.w);
  r[4] = (short)bf16rne(b.x); r[5] = (short)bf16rne(b.y);
  r[6] = (short)bf16rne(b.z); r[7] = (short)bf16rne(b.w);
  return r;
}

// ------------------------------------------------------------------
// P0: swizzle weights fp32 -> bf16 B-fragment layout.
// ------------------------------------------------------------------
__global__ __launch_bounds__(256) void prep_weights(
    const float* __restrict__ Wq, const float* __restrict__ Wk,
    const float* __restrict__ Wv, const float* __restrict__ Wo,
    unsigned short* __restrict__ dst) {
  const int i = blockIdx.x * 256 + threadIdx.x;
  const int w = i >> 14, e = i & 16383;
  const int k = e >> 7, n = e & 127;
  const float* src = (w == 0) ? Wq : (w == 1) ? Wk : (w == 2) ? Wv : Wo;
  dst[w * 16384 + (((k >> 3) * 128 + n) << 3) + (k & 7)] = bf16rne(src[e]);
}

// ------------------------------------------------------------------
// Sort pipeline
// ------------------------------------------------------------------
__global__ __launch_bounds__(256) void zero_cnt(int* __restrict__ cnt) {
  cnt[blockIdx.x * 256 + threadIdx.x] = 0;
}

__global__ __launch_bounds__(256) void bucketize_count(
    const float* __restrict__ xc_off, int* __restrict__ seg_arr,
    int* __restrict__ cnt) {
  const int tok = blockIdx.x * 256 + threadIdx.x;
  const int b = tok >> 14;
  // EXACT replication of reference fp32 bucketize math
  const float sp = 1.0f / 63.0f;
  const float half = sp * 0.5f;
  const float x0 = xc_off[(size_t)tok * 2 + 0];
  const float x1 = xc_off[(size_t)tok * 2 + 1];
  float n0 = floorf((x0 - 0.0f + half) / sp);
  float n1 = floorf((x1 - 0.0f + half) / sp);
  n0 = fminf(fmaxf(n0, 0.0f), 63.0f);
  n1 = fminf(fmaxf(n1, 0.0f), 63.0f);
  const int seg = b * S_ + (int)(n0 * 64.0f + n1);
  seg_arr[tok] = seg;
  atomicAdd(&cnt[seg], 1);
}

__global__ __launch_bounds__(1024) void scan_kernel(
    const int* __restrict__ cnt, int* __restrict__ offs, int* __restrict__ cursor) {
  __shared__ int sh[1024];
  const int tid = threadIdx.x;
  const int base = tid * 32;
  int local[32];
  int tot = 0;
#pragma unroll
  for (int i = 0; i < 32; ++i) { local[i] = cnt[base + i]; tot += local[i]; }
  sh[tid] = tot;
  __syncthreads();
  for (int ofs = 1; ofs < 1024; ofs <<= 1) {
    int v = (tid >= ofs) ? sh[tid - ofs] : 0;
    __syncthreads();
    sh[tid] += v;
    __syncthreads();
  }
  int run = sh[tid] - tot;
#pragma unroll
  for (int i = 0; i < 32; ++i) {
    offs[base + i] = run;
    cursor[base + i] = run;
    run += local[i];
  }
  if (tid == 1023) offs[NCELL] = run;
}

__global__ __launch_bounds__(256) void scatter_ids(
    const int* __restrict__ seg_arr, int* __restrict__ cursor,
    int* __restrict__ sorted) {
  const int tok = blockIdx.x * 256 + threadIdx.x;
  const int seg = seg_arr[tok];
  const int r = atomicAdd(&cursor[seg], 1);
  sorted[r] = tok;
}

// ------------------------------------------------------------------
// K0: Qp = 0.25 * latents @ Wq, stored transposed-in-row: Qp[s][d*8+h]
// ------------------------------------------------------------------
__global__ __launch_bounds__(512, 4) void qproj_mfma(
    const float* __restrict__ latents, const unsigned short* __restrict__ Wq_sw,
    float* __restrict__ Qp) {
  __shared__ __align__(16) unsigned short wq[16384];
  const int tid = threadIdx.x;
  {
    const uint4* s = (const uint4*)Wq_sw;
    uint4* d = (uint4*)wq;
#pragma unroll
    for (int i = 0; i < 4; ++i) d[i * 512 + tid] = s[i * 512 + tid];
  }
  __syncthreads();

  const int wave = tid >> 6, lane = tid & 63;
  const int c = lane & 15, g = lane >> 4;
  const int t0w = blockIdx.x * 128 + wave * 16;

  f32x4 acc[8];
#pragma unroll
  for (int i = 0; i < 8; ++i) acc[i] = {0.f, 0.f, 0.f, 0.f};

  const float* arow = latents + (size_t)(t0w + c) * E_ + g * 8;
  const bf16x8* bq = (const bf16x8*)wq;
#pragma unroll
  for (int ks = 0; ks < 4; ++ks) {
    float4 a0 = *(const float4*)(arow + ks * 32);
    float4 a1 = *(const float4*)(arow + ks * 32 + 4);
    bf16x8 af = pack8(a0, a1);
    const int bo = (ks * 4 + g) * 128 + c;
#pragma unroll
    for (int nt = 0; nt < 8; ++nt)
      acc[nt] = __builtin_amdgcn_mfma_f32_16x16x32_bf16(af, bq[bo + nt * 16], acc[nt], 0, 0, 0);
  }
#pragma unroll
  for (int nt = 0; nt < 8; ++nt)
#pragma unroll
    for (int r = 0; r < 4; ++r)
      Qp[(size_t)(t0w + g * 4 + r) * E_ + c * 8 + nt] = acc[nt][r] * 0.25f;
}

// ------------------------------------------------------------------
// KF: fused per-cell kernel, persistent grid, per-head K->w->V fusion
// to keep register pressure < 128 (no spills). Zero scatter atomics.
// ------------------------------------------------------------------
__global__ __launch_bounds__(512, 4) void fused_cells(
    const float* __restrict__ zc_off, const float* __restrict__ zc_on,
    const float* __restrict__ fake, const int* __restrict__ ignore_flag,
    const unsigned short* __restrict__ Wk_sw, const unsigned short* __restrict__ Wv_sw,
    const float* __restrict__ Qp, const int* __restrict__ offs,
    const int* __restrict__ sorted, float* __restrict__ out) {
  __shared__ __align__(16) unsigned short wk[16384];
  __shared__ __align__(16) unsigned short wv[16384];
  const int tid = threadIdx.x;
  {
    const uint4* sk = (const uint4*)Wk_sw;
    const uint4* sv = (const uint4*)Wv_sw;
    uint4* dk = (uint4*)wk; uint4* dv = (uint4*)wv;
#pragma unroll
    for (int i = 0; i < 4; ++i) {
      dk[i * 512 + tid] = sk[i * 512 + tid];
      dv[i * 512 + tid] = sv[i * 512 + tid];
    }
  }
  const int ign = *ignore_flag;
  __syncthreads();

  const int wave = tid >> 6, lane = tid & 63;
  const int c = lane & 15, g = lane >> 4;
  const bf16x8* bk = (const bf16x8*)wk;
  const bf16x8* bv = (const bf16x8*)wv;

  for (int grp = blockIdx.x; grp < NCELL / 8; grp += FUSED_GRID) {
    const int cell = grp * 8 + wave;
    const int s = cell & (S_ - 1);
    const int base = offs[cell];
    const int n_off = offs[cell + 1] - base;
    const float* qrow = Qp + (size_t)s * E_ + c * 8;   // qrow[h] = q[h*16+c]

    float num_acc[8], den_acc[8];
#pragma unroll
    for (int i = 0; i < 8; ++i) { num_acc[i] = 0.f; den_acc[i] = 0.f; }

    const int chunks = (n_off + 16) >> 4;

    for (int ch = 0; ch < chunks; ++ch) {
      const int idx = ch * 16 + c;
      const float* arow;
      if (idx < n_off)       arow = zc_off + (size_t)sorted[base + idx] * E_;
      else if (idx == n_off) arow = ign ? fake : (zc_on + (size_t)cell * E_);
      else                   arow = zc_on;   // pad: weight forced to 0
      arow += g * 8;

      // A-fragments for this chunk (16 VGPRs)
      bf16x8 af[4];
#pragma unroll
      for (int ks = 0; ks < 4; ++ks) {
        float4 a0 = *(const float4*)(arow + ks * 32);
        float4 a1 = *(const float4*)(arow + ks * 32 + 4);
        af[ks] = pack8(a0, a1);
      }

      // per-head: K-MFMA -> scores -> V-MFMA -> accumulate
#pragma unroll 2
      for (int h = 0; h < 8; ++h) {
        const int bo = g * 128 + c + h * 16;
        f32x4 aK = {0.f, 0.f, 0.f, 0.f};
#pragma unroll
        for (int ks = 0; ks < 4; ++ks)
          aK = __builtin_amdgcn_mfma_f32_16x16x32_bf16(af[ks], bk[bo + ks * 512], aK, 0, 0, 0);

        const float qv = qrow[h];   // L1-hot 4B load
        float w[4];
#pragma unroll
        for (int r = 0; r < 4; ++r) {
          float p = aK[r] * qv;
          p += __shfl_xor(p, 1, 64); p += __shfl_xor(p, 2, 64);
          p += __shfl_xor(p, 4, 64); p += __shfl_xor(p, 8, 64);
          const int tr = ch * 16 + g * 4 + r;
          w[r] = (tr <= n_off) ? __expf(p) : 0.f;
        }

        f32x4 aV = {0.f, 0.f, 0.f, 0.f};
#pragma unroll
        for (int ks = 0; ks < 4; ++ks)
          aV = __builtin_amdgcn_mfma_f32_16x16x32_bf16(af[ks], bv[bo + ks * 512], aV, 0, 0, 0);

        float sv = 0.f, sd = 0.f;
#pragma unroll
        for (int r = 0; r < 4; ++r) { sv = fmaf(w[r], aV[r], sv); sd += w[r]; }
        num_acc[h] += sv;
        den_acc[h] += sd;
      }
    }

    // reduce over g (lane bits 4..5), normalize, store
#pragma unroll
    for (int i = 0; i < 8; ++i) {
      num_acc[i] += __shfl_xor(num_acc[i], 16, 64);
      num_acc[i] += __shfl_xor(num_acc[i], 32, 64);
      den_acc[i] += __shfl_xor(den_acc[i], 16, 64);
      den_acc[i] += __shfl_xor(den_acc[i], 32, 64);
    }
#pragma unroll
    for (int b = 0; b < 2; ++b) {
      const int nt = 2 * g + b;
      out[(size_t)cell * E_ + nt * 16 + c] = num_acc[nt] / den_acc[nt];
    }
  }
}

// ------------------------------------------------------------------
// K3: finalize in-place: out = out @ Wo   (out already normalized)
// ------------------------------------------------------------------
__global__ __launch_bounds__(512, 4) void finalize_mfma(
    const unsigned short* __restrict__ Wo_sw, float* __restrict__ out) {
  __shared__ __align__(16) unsigned short wo[16384];
  const int tid = threadIdx.x;
  {
    const uint4* s = (const uint4*)Wo_sw;
    uint4* d = (uint4*)wo;
#pragma unroll
    for (int i = 0; i < 4; ++i) d[i * 512 + tid] = s[i * 512 + tid];
  }
  __syncthreads();

  const int wave = tid >> 6, lane = tid & 63;
  const int c = lane & 15, g = lane >> 4;
  const int t0w = blockIdx.x * 128 + wave * 16;

  f32x4 acc[8];
#pragma unroll
  for (int i = 0; i < 8; ++i) acc[i] = {0.f, 0.f, 0.f, 0.f};

  const float* nrow = out + (size_t)(t0w + c) * E_ + g * 8;
  const bf16x8* bo_ = (const bf16x8*)wo;
#pragma unroll
  for (int ks = 0; ks < 4; ++ks) {
    float4 a0 = *(const float4*)(nrow + ks * 32);
    float4 a1 = *(const float4*)(nrow + ks * 32 + 4);
    bf16x8 af = pack8(a0, a1);
    const int bofs = (ks * 4 + g) * 128 + c;
#pragma unroll
    for (int nt = 0; nt < 8; ++nt)
      acc[nt] = __builtin_amdgcn_mfma_f32_16x16x32_bf16(af, bo_[bofs + nt * 16], acc[nt], 0, 0, 0);
  }
#pragma unroll
  for (int nt = 0; nt < 8; ++nt)
#pragma unroll
    for (int r = 0; r < 4; ++r)
      out[(size_t)(t0w + g * 4 + r) * E_ + nt * 16 + c] = acc[nt][r];
}

// ------------------------------------------------------------------
extern "C" void kernel_launch(void* const* d_in, const int* in_sizes, int n_in,
                              void* d_out, int out_size, void* d_ws, size_t ws_size,
                              hipStream_t stream) {
  const float* xc_off  = (const float*)d_in[0];
  const float* zc_off  = (const float*)d_in[2];
  const float* zc_on   = (const float*)d_in[3];
  const float* latents = (const float*)d_in[4];
  const float* fake    = (const float*)d_in[5];
  const float* Wq      = (const float*)d_in[6];
  const float* Wk      = (const float*)d_in[7];
  const float* Wv      = (const float*)d_in[8];
  const float* Wo      = (const float*)d_in[9];
  const int*   ignore  = (const int*)d_in[10];

  float* out = (float*)d_out;

  // workspace layout
  float* Qp = (float*)d_ws;                                  // S*E fp32 (2 MB)
  unsigned short* Wsw = (unsigned short*)(Qp + (size_t)S_ * E_);
  int* seg_arr = (int*)(Wsw + 65536);
  int* cnt     = seg_arr + NTOK;
  int* offs    = cnt + NCELL;
  int* cursor  = offs + NCELL + 2;
  int* sorted  = cursor + NCELL;
  unsigned short* Wq_sw = Wsw;
  unsigned short* Wk_sw = Wsw + 16384;
  unsigned short* Wv_sw = Wsw + 32768;
  unsigned short* Wo_sw = Wsw + 49152;

  prep_weights<<<256, 256, 0, stream>>>(Wq, Wk, Wv, Wo, Wsw);
  zero_cnt<<<NCELL / 256, 256, 0, stream>>>(cnt);
  bucketize_count<<<NTOK / 256, 256, 0, stream>>>(xc_off, seg_arr, cnt);
  scan_kernel<<<1, 1024, 0, stream>>>(cnt, offs, cursor);
  scatter_ids<<<NTOK / 256, 256, 0, stream>>>(seg_arr, cursor, sorted);
  qproj_mfma<<<S_ / 128, 512, 0, stream>>>(latents, Wq_sw, Qp);
  fused_cells<<<FUSED_GRID, 512, 0, stream>>>(zc_off, zc_on, fake, ignore,
                                              Wk_sw, Wv_sw, Qp, offs, sorted, out);
  finalize_mfma<<<NCELL / 128, 512, 0, stream>>>(Wo_sw, out);
}